// Round 28
// baseline (130.665 us; speedup 1.0000x reference)
//
#include <hip/hip_runtime.h>
#include <stdint.h>

typedef __attribute__((ext_vector_type(8))) short short8;
typedef __attribute__((ext_vector_type(4))) float floatx4;
typedef __attribute__((ext_vector_type(16))) float floatx16;

__device__ __forceinline__ float b2f(unsigned short u) {
    union { unsigned int i; float f; } x; x.i = ((unsigned int)u) << 16; return x.f;
}
__device__ __forceinline__ unsigned short f2b(float f) {
    unsigned int x = __float_as_uint(f);
    return (unsigned short)((x + 0x7FFFu + ((x >> 16) & 1u)) >> 16);
}
__device__ __forceinline__ unsigned int cvt_pk_bf16(float lo, float hi) {
    unsigned int r;
    asm("v_cvt_pk_bf16_f32 %0, %1, %2" : "=v"(r) : "v"(lo), "v"(hi));
    return r;
}
__device__ __forceinline__ float exp2_(float x) {
    float r;
    asm("v_exp_f32 %0, %1" : "=v"(r) : "v"(x));
    return r;
}

__device__ __forceinline__ void gload_lds16(const void* g, void* l) {
    __builtin_amdgcn_global_load_lds((const __attribute__((address_space(1))) unsigned int*)g,
                                     (__attribute__((address_space(3))) unsigned int*)l, 16, 0, 0);
}

// ---------------- fused prep: 4 weight transposes (f32->bf16) + hs cast, one launch ----------------
__global__ __launch_bounds__(256)
void prep_kernel(const float* __restrict__ Wq, const float* __restrict__ Wk,
                 const float* __restrict__ Wv, const float* __restrict__ Wo,
                 const float* __restrict__ hs,
                 unsigned short* __restrict__ Wqkv, unsigned short* __restrict__ WoT,
                 unsigned short* __restrict__ hs_b) {
    __shared__ float tile[64][65];
    int b = blockIdx.x;
    if (b >= 2560) {
        int i = ((b - 2560) * 256 + threadIdx.x) * 4;
        float4 v = *reinterpret_cast<const float4*>(hs + i);
        hs_b[i + 0] = f2b(v.x);
        hs_b[i + 1] = f2b(v.y);
        hs_b[i + 2] = f2b(v.z);
        hs_b[i + 3] = f2b(v.w);
        return;
    }
    const float* in;
    unsigned short* out;
    int bx, by, ld_in, ld_out;
    if (b < 1024) {
        in = Wq; out = Wqkv; bx = b & 31; by = b >> 5; ld_in = 2048; ld_out = 2048;
    } else if (b < 1280) {
        int c = b - 1024;
        in = Wk; out = Wqkv + (size_t)2048 * 2048; bx = c & 7; by = c >> 3; ld_in = 512; ld_out = 2048;
    } else if (b < 1536) {
        int c = b - 1280;
        in = Wv; out = Wqkv + (size_t)2560 * 2048; bx = c & 7; by = c >> 3; ld_in = 512; ld_out = 2048;
    } else {
        int c = b - 1536;
        in = Wo; out = WoT; bx = c & 31; by = c >> 5; ld_in = 2048; ld_out = 2048;
    }
    int tx = threadIdx.x & 63, ty = threadIdx.x >> 6;
    int c0 = bx * 64, r0 = by * 64;
    #pragma unroll
    for (int i = 0; i < 64; i += 4)
        tile[ty + i][tx] = in[(size_t)(r0 + ty + i) * ld_in + c0 + tx];
    __syncthreads();
    #pragma unroll
    for (int i = 0; i < 64; i += 4)
        out[(size_t)(c0 + ty + i) * ld_out + r0 + tx] = f2b(tile[tx][ty + i]);
}

// ---------------- QKV GEMM: 64x64 tile, BK=64, 4 waves (2x2, wave tile 32x32) ----------------
// Grid 48x32 = 1536 blocks (5 resident/CU by LDS). Each 64-col block = exactly one head:
//   nb <  2048: Q block -> RoPE fused (pair spans wave w and w^1), scaled, bf16 to qkv
//   nb in [2048,2560): K block -> RoPE fused, written to fragment-native kB
//   nb >= 2560: V block -> fragment-native vB packed write
__global__ __launch_bounds__(256)
void gemm64x64_qkv(const unsigned short* __restrict__ A, const unsigned short* __restrict__ BT,
                   unsigned short* __restrict__ Cout, unsigned short* __restrict__ vTout,
                   unsigned short* __restrict__ kBout, const int* __restrict__ pos_ids,
                   int M, int N, int K) {
    __shared__ __align__(16) unsigned short As[2][64 * 64];
    __shared__ __align__(16) unsigned short Bs[2][64 * 64];
    int tid = threadIdx.x;
    int l = tid & 63, w = tid >> 6;
    int lr = l & 15, lg = l >> 4;
    int wr = w >> 1, wc = w & 1;

    int gx = gridDim.x;
    int nwg = gx * gridDim.y;
    int flat = blockIdx.y * gx + blockIdx.x;
    int q8 = nwg >> 3;
    int f2 = (flat & 7) * q8 + (flat >> 3);
    int bx = f2 % gx, by = f2 / gx;
    int nb = bx * 64, mb = by * 64;

    floatx4 acc[2][2];
    #pragma unroll
    for (int m = 0; m < 2; ++m)
        #pragma unroll
        for (int f = 0; f < 2; ++f) acc[m][f] = (floatx4)(0.f);

    // staging: A,B each 512 chunks (2/thread); rows of 8x16B slots, slot^(row&7) swizzle
    const unsigned short* Ag[2];
    const unsigned short* Bg[2];
    #pragma unroll
    for (int i = 0; i < 2; ++i) {
        int c = tid + 256 * i;
        int r = c >> 3, j = (c & 7) ^ (r & 7);
        Ag[i] = A + (size_t)(mb + r) * K + j * 8;
        Bg[i] = BT + (size_t)(nb + r) * K + j * 8;
    }

    auto stage = [&](int buf, int kb) {
        #pragma unroll
        for (int i = 0; i < 2; ++i) {
            gload_lds16(Ag[i] + kb, &As[buf][(tid + 256 * i) * 8]);
            gload_lds16(Bg[i] + kb, &Bs[buf][(tid + 256 * i) * 8]);
        }
    };

    int nsteps = K >> 6;
    stage(0, 0);
    for (int it = 0; it < nsteps; ++it) {
        int nxt = (it + 1 < nsteps) ? it + 1 : it;
        stage((it + 1) & 1, nxt * 64);
        asm volatile("s_waitcnt vmcnt(4)" ::: "memory"); // cur 4 landed; next 4 in flight
        __builtin_amdgcn_s_barrier();
        __builtin_amdgcn_sched_barrier(0);

        const unsigned short* Ab = As[it & 1];
        const unsigned short* Bb = Bs[it & 1];
        #pragma unroll
        for (int kh = 0; kh < 2; ++kh) {
            int sl = ((kh * 4 + lg) ^ (lr & 7)) * 8;
            short8 af[2], bf[2];
            #pragma unroll
            for (int m = 0; m < 2; ++m)
                af[m] = *reinterpret_cast<const short8*>(Ab + (wr * 32 + m * 16 + lr) * 64 + sl);
            #pragma unroll
            for (int f = 0; f < 2; ++f)
                bf[f] = *reinterpret_cast<const short8*>(Bb + (wc * 32 + f * 16 + lr) * 64 + sl);
            #pragma unroll
            for (int m = 0; m < 2; ++m)
                #pragma unroll
                for (int f = 0; f < 2; ++f)
                    acc[m][f] = __builtin_amdgcn_mfma_f32_16x16x32_bf16(af[m], bf[f], acc[m][f], 0, 0, 0);
        }
        __builtin_amdgcn_sched_barrier(0);
        __builtin_amdgcn_s_barrier();
    }
    asm volatile("s_waitcnt vmcnt(0)" ::: "memory");

    if (nb < 2560) {
        // ---- Q or K block (one head): fused RoPE. Pair (i, i+32) spans waves (w, w^1). ----
        float* Xs = (float*)&As[0][0];   // 8KB scratch in dead A buffer
        __syncthreads();                 // all waves' final staging writes landed
        if (w & 1) {                     // wc==1: deposit x2 halves
            float* dst = Xs + ((size_t)(w >> 1) * 64 + l) * 16;
            #pragma unroll
            for (int m = 0; m < 2; ++m)
                #pragma unroll
                for (int f = 0; f < 2; ++f)
                    #pragma unroll
                    for (int r = 0; r < 4; ++r)
                        dst[m * 8 + f * 4 + r] = acc[m][f][r];
        }
        __syncthreads();
        if (!(w & 1)) {                  // wc==0: rotate and write both halves
            const float* src = Xs + ((size_t)(w >> 1) * 64 + l) * 16;
            bool isQ = (nb < 2048);
            float qs = isQ ? 0.18033688011112042f : 1.0f; // (1/8)*log2(e) for Q
            int kvh = isQ ? 0 : ((nb - 2048) >> 6);
            #pragma unroll
            for (int f = 0; f < 2; ++f) {
                int i = f * 16 + lr;                       // head-relative d, < 32
                float invf = exp2f(-0.41524101186092029f * (float)i);
                int ocol = nb + f * 16 + lr;               // wc==0 columns
                #pragma unroll
                for (int m = 0; m < 2; ++m) {
                    int orow = mb + (w >> 1) * 32 + m * 16 + lg * 4;
                    #pragma unroll
                    for (int r = 0; r < 4; ++r) {
                        int s = orow + r;
                        float pos = (float)pos_ids[s];
                        float sn, cs;
                        __sincosf(pos * invf, &sn, &cs);
                        float x1 = acc[m][f][r];
                        float x2 = src[m * 8 + f * 4 + r];
                        float r1 = (x1 * cs - x2 * sn) * qs;
                        float r2 = (x2 * cs + x1 * sn) * qs;
                        if (isQ) {
                            Cout[(size_t)s * N + ocol]      = f2b(r1);
                            Cout[(size_t)s * N + ocol + 32] = f2b(r2);
                        } else {
                            int t32 = s >> 5, lq2 = s & 31;
                            int d1 = i, d2 = i + 32;
                            int dc1 = d1 >> 4, hl1 = (d1 >> 3) & 1, e1 = d1 & 7;
                            int dc2 = d2 >> 4, hl2 = (d2 >> 3) & 1, e2 = d2 & 7;
                            size_t tb = (size_t)(kvh * 64 + t32) * 2048;
                            kBout[tb + (size_t)dc1 * 512 + (hl1 * 32 + lq2) * 8 + e1] = f2b(r1);
                            kBout[tb + (size_t)dc2 * 512 + (hl2 * 32 + lq2) * 8 + e2] = f2b(r2);
                        }
                    }
                }
            }
        }
        return;
    }

    // ---- V block: fragment-native vB packed write ----
    #pragma unroll
    for (int m = 0; m < 2; ++m) {
        int orow = mb + wr * 32 + m * 16 + lg * 4;
        #pragma unroll
        for (int f = 0; f < 2; ++f) {
            int ocol = nb + wc * 32 + f * 16 + lr;
            int d = ocol - 2560;
            int kvh2 = d >> 6, dd = d & 63, dh = dd >> 5, lq2 = dd & 31;
            int t64 = orow >> 6, so = orow & 63;
            int w2 = so >> 5, so32 = so & 31, kc = so32 >> 4, so16 = so32 & 15;
            int hl2 = so16 >> 3, e0 = so16 & 7;
            size_t addr = ((size_t)((kvh2 * 32 + t64) * 8) + w2 * 4 + dh * 2 + kc) * 512
                        + (hl2 * 32 + lq2) * 8 + e0;
            unsigned long long pk =
                (unsigned long long)cvt_pk_bf16(acc[m][f][0], acc[m][f][1])
              | ((unsigned long long)cvt_pk_bf16(acc[m][f][2], acc[m][f][3]) << 32);
            *reinterpret_cast<unsigned long long*>(vTout + addr) = pk;
        }
    }
}

// ---------------- O-proj GEMM: 64x64 tile (round-27, proven) ----------------
__global__ __launch_bounds__(256)
void gemm64x64_o(const unsigned short* __restrict__ A, const unsigned short* __restrict__ BT,
                 float* __restrict__ Cout, int M, int N, int K) {
    __shared__ __align__(16) unsigned short As[2][64 * 64];
    __shared__ __align__(16) unsigned short Bs[2][64 * 64];
    int tid = threadIdx.x;
    int l = tid & 63, w = tid >> 6;
    int lr = l & 15, lg = l >> 4;
    int wr = w >> 1, wc = w & 1;

    int gx = gridDim.x;
    int nwg = gx * gridDim.y;
    int flat = blockIdx.y * gx + blockIdx.x;
    int q8 = nwg >> 3;
    int f2 = (flat & 7) * q8 + (flat >> 3);
    int bx = f2 % gx, by = f2 / gx;
    int nb = bx * 64, mb = by * 64;

    floatx4 acc[2][2];
    #pragma unroll
    for (int m = 0; m < 2; ++m)
        #pragma unroll
        for (int f = 0; f < 2; ++f) acc[m][f] = (floatx4)(0.f);

    const unsigned short* Ag[2];
    const unsigned short* Bg[2];
    #pragma unroll
    for (int i = 0; i < 2; ++i) {
        int c = tid + 256 * i;
        int r = c >> 3, j = (c & 7) ^ (r & 7);
        Ag[i] = A + (size_t)(mb + r) * K + j * 8;
        Bg[i] = BT + (size_t)(nb + r) * K + j * 8;
    }

    auto stage = [&](int buf, int kb) {
        #pragma unroll
        for (int i = 0; i < 2; ++i) {
            gload_lds16(Ag[i] + kb, &As[buf][(tid + 256 * i) * 8]);
            gload_lds16(Bg[i] + kb, &Bs[buf][(tid + 256 * i) * 8]);
        }
    };

    int nsteps = K >> 6;
    stage(0, 0);
    for (int it = 0; it < nsteps; ++it) {
        int nxt = (it + 1 < nsteps) ? it + 1 : it;
        stage((it + 1) & 1, nxt * 64);
        asm volatile("s_waitcnt vmcnt(4)" ::: "memory");
        __builtin_amdgcn_s_barrier();
        __builtin_amdgcn_sched_barrier(0);

        const unsigned short* Ab = As[it & 1];
        const unsigned short* Bb = Bs[it & 1];
        #pragma unroll
        for (int kh = 0; kh < 2; ++kh) {
            int sl = ((kh * 4 + lg) ^ (lr & 7)) * 8;
            short8 af[2], bf[2];
            #pragma unroll
            for (int m = 0; m < 2; ++m)
                af[m] = *reinterpret_cast<const short8*>(Ab + (wr * 32 + m * 16 + lr) * 64 + sl);
            #pragma unroll
            for (int f = 0; f < 2; ++f)
                bf[f] = *reinterpret_cast<const short8*>(Bb + (wc * 32 + f * 16 + lr) * 64 + sl);
            #pragma unroll
            for (int m = 0; m < 2; ++m)
                #pragma unroll
                for (int f = 0; f < 2; ++f)
                    acc[m][f] = __builtin_amdgcn_mfma_f32_16x16x32_bf16(af[m], bf[f], acc[m][f], 0, 0, 0);
        }
        __builtin_amdgcn_sched_barrier(0);
        __builtin_amdgcn_s_barrier();
    }
    asm volatile("s_waitcnt vmcnt(0)" ::: "memory");

    #pragma unroll
    for (int m = 0; m < 2; ++m) {
        int orow = mb + wr * 32 + m * 16 + lg * 4;
        #pragma unroll
        for (int f = 0; f < 2; ++f) {
            int ocol = nb + wc * 32 + f * 16 + lr;
            #pragma unroll
            for (int r = 0; r < 4; ++r)
                Cout[(size_t)(orow + r) * N + ocol] = acc[m][f][r];
        }
    }
}

// ---------------- causal GQA flash attention (round-20, proven): all-register, coalesced K+V ----------------
__global__ __launch_bounds__(128, 2)
void attn_kernel(const unsigned short* __restrict__ QKV, // [2048][3072] bf16 (q only used)
                 const unsigned short* __restrict__ KB,  // kB fragment layout, 2MB
                 const unsigned short* __restrict__ VB,  // vB fragment layout, 2MB
                 unsigned short* __restrict__ O) {       // [2048][2048] bf16
    const int LDQ = 3072, HID = 2048;
    __shared__ float Ms[64 * 36];

    int tid = threadIdx.x;
    int l = tid & 63, w = tid >> 6;        // 2 waves
    int lq = l & 31, hl = l >> 5;
    int b = blockIdx.x;
    int h = b & 31;
    int band = 63 - (b >> 5);               // heavy bands first
    int nT = (band >> 1) + 1;               // 64-key tiles
    int kvh = h >> 2;
    int qrow = band * 32 + lq;

    short8 qf[4];
    {
        const unsigned short* Qr = QKV + (size_t)qrow * LDQ + h * 64;
        #pragma unroll
        for (int c = 0; c < 4; ++c)
            qf[c] = *reinterpret_cast<const short8*>(Qr + c * 16 + hl * 8);
    }

    const unsigned short* Kp = KB + ((size_t)(kvh * 64 + w) * 4) * 512 + l * 8;
    const size_t KSTEP = 2 * 4 * 512;
    const unsigned short* Vbase = VB + ((size_t)kvh * 32 * 8 + (size_t)w * 4) * 512 + l * 8;

    floatx16 acc[2];
    acc[0] = (floatx16)(0.f); acc[1] = (floatx16)(0.f);
    float m_run = -1e30f, l_run = 0.f;

    auto process = [&](const short8* kf, int c0w, bool diag,
                       short8 v00, short8 v01, short8 v10, short8 v11) {
        floatx16 st = (floatx16)(0.f);
        __builtin_amdgcn_s_setprio(1);
        #pragma unroll
        for (int dc = 0; dc < 4; ++dc)
            st = __builtin_amdgcn_mfma_f32_32x32x16_bf16(kf[dc], qf[dc], st, 0, 0, 0);
        __builtin_amdgcn_s_setprio(0);
        if (diag) {
            #pragma unroll
            for (int r = 0; r < 16; ++r) {
                int key = c0w + (r & 3) + 8 * (r >> 2) + 4 * hl;
                if (key > qrow) st[r] = -1e30f;
            }
        }
        float t0 = fmaxf(fmaxf(st[0], st[1]), fmaxf(st[2], st[3]));
        float t1 = fmaxf(fmaxf(st[4], st[5]), fmaxf(st[6], st[7]));
        float t2 = fmaxf(fmaxf(st[8], st[9]), fmaxf(st[10], st[11]));
        float t3 = fmaxf(fmaxf(st[12], st[13]), fmaxf(st[14], st[15]));
        float tm = fmaxf(fmaxf(t0, t1), fmaxf(t2, t3));
        tm = fmaxf(tm, __shfl_xor(tm, 32));
        if (!__all(tm <= m_run + 11.5f)) {
            float mn = fmaxf(m_run, tm);
            float al = exp2_(m_run - mn);
            l_run *= al;
            acc[0] *= al;
            acc[1] *= al;
            m_run = mn;
        }
        float p[16];
        #pragma unroll
        for (int r = 0; r < 16; ++r) p[r] = exp2_(st[r] - m_run);
        float s0 = (p[0] + p[1]) + (p[2] + p[3]);
        float s1 = (p[4] + p[5]) + (p[6] + p[7]);
        float s2 = (p[8] + p[9]) + (p[10] + p[11]);
        float s3 = (p[12] + p[13]) + (p[14] + p[15]);
        float rs = (s0 + s1) + (s2 + s3);
        rs += __shfl_xor(rs, 32);
        l_run += rs;
        unsigned int u[4][2];
        #pragma unroll
        for (int B2 = 0; B2 < 4; ++B2) {
            u[B2][0] = cvt_pk_bf16(p[B2 * 4 + 0], p[B2 * 4 + 1]);
            u[B2][1] = cvt_pk_bf16(p[B2 * 4 + 2], p[B2 * 4 + 3]);
        }
        asm volatile("s_waitcnt vmcnt(4)" ::: "memory"); // V(j) landed; K(j+1) in flight
        __builtin_amdgcn_sched_barrier(0);
        #pragma unroll
        for (int kc = 0; kc < 2; ++kc) {
            unsigned int o0 = u[2 * kc][0],     o1 = u[2 * kc][1];
            unsigned int e0 = u[2 * kc + 1][0], e1 = u[2 * kc + 1][1];
            unsigned int t0x = (unsigned int)__shfl((int)o0, l ^ 32);
            unsigned int t1x = (unsigned int)__shfl((int)o1, l ^ 32);
            unsigned int s0p = (unsigned int)__shfl((int)e0, l ^ 32);
            unsigned int s1p = (unsigned int)__shfl((int)e1, l ^ 32);
            union { unsigned int uu[4]; short8 s8; } pf;
            pf.uu[0] = hl ? s0p : o0;
            pf.uu[1] = hl ? s1p : o1;
            pf.uu[2] = hl ? e0 : t0x;
            pf.uu[3] = hl ? e1 : t1x;
            __builtin_amdgcn_s_setprio(1);
            acc[0] = __builtin_amdgcn_mfma_f32_32x32x16_bf16(kc ? v01 : v00, pf.s8, acc[0], 0, 0, 0);
            acc[1] = __builtin_amdgcn_mfma_f32_32x32x16_bf16(kc ? v11 : v10, pf.s8, acc[1], 0, 0, 0);
            __builtin_amdgcn_s_setprio(0);
        }
    };

    short8 kA[4], kBr[4];
    #pragma unroll
    for (int dc = 0; dc < 4; ++dc)
        kA[dc] = *reinterpret_cast<const short8*>(Kp + dc * 512);

    int j = 0;
    while (true) {
        {
            bool last = (j == nT - 1);
            const unsigned short* Vs = Vbase + (size_t)j * 8 * 512;
            short8 v00 = *reinterpret_cast<const short8*>(Vs);
            short8 v01 = *reinterpret_cast<const short8*>(Vs + 512);
            short8 v10 = *reinterpret_cast<const short8*>(Vs + 1024);
            short8 v11 = *reinterpret_cast<const short8*>(Vs + 1536);
            __builtin_amdgcn_sched_barrier(0);
            const unsigned short* Kn = last ? Kp : Kp + KSTEP;
            #pragma unroll
            for (int dc = 0; dc < 4; ++dc)
                kBr[dc] = *reinterpret_cast<const short8*>(Kn + dc * 512);
            asm volatile("s_waitcnt vmcnt(8)" ::: "memory");
            __builtin_amdgcn_sched_barrier(0);
            process(kA, j * 64 + w * 32, last, v00, v01, v10, v11);
            if (last) break;
            ++j; Kp = Kn;
        }
        {
            bool last = (j == nT - 1);
            const unsigned short* Vs = Vbase + (size_t)j * 8 * 512;
            short8 v00 = *reinterpret_cast<const short8*>(Vs);
            short8 v01 = *reinterpret_cast<const short8*>(Vs + 512);
            short8 v10 = *reinterpret_cast<const short8*>(Vs + 1024);
            short8 v11 = *reinterpret_cast<const short8*>(Vs + 1536);
            __builtin_amdgcn_sched_barrier(0);
            const unsigned short* Kn = last ? Kp : Kp + KSTEP;
            #pragma unroll
            for (int dc = 0; dc < 4; ++dc)
                kA[dc] = *reinterpret_cast<const short8*>(Kn + dc * 512);
            asm volatile("s_waitcnt vmcnt(8)" ::: "memory");
            __builtin_amdgcn_sched_barrier(0);
            process(kBr, j * 64 + w * 32, last, v00, v01, v10, v11);
            if (last) break;
            ++j; Kp = Kn;
        }
    }
    asm volatile("s_waitcnt vmcnt(0)" ::: "memory");
    __syncthreads();

    if (w == 1) {
        Ms[l * 36 + 0] = m_run;
        Ms[l * 36 + 1] = l_run;
        #pragma unroll
        for (int d = 0; d < 2; ++d)
            #pragma unroll
            for (int r = 0; r < 16; ++r)
                Ms[l * 36 + 2 + d * 16 + r] = acc[d][r];
    }
    __syncthreads();
    if (w == 0) {
        float m1 = Ms[l * 36 + 0], l1 = Ms[l * 36 + 1];
        float mm = fmaxf(m_run, m1);
        float a0 = exp2_(m_run - mm), a1 = exp2_(m1 - mm);
        float inv = 1.0f / (l_run * a0 + l1 * a1);
        a0 *= inv; a1 *= inv;
        unsigned short* Op = O + (size_t)qrow * HID + h * 64 + hl * 4;
        #pragma unroll
        for (int d = 0; d < 2; ++d)
            #pragma unroll
            for (int g4 = 0; g4 < 4; ++g4) {
                float v0 = acc[d][g4 * 4 + 0] * a0 + Ms[l * 36 + 2 + d * 16 + g4 * 4 + 0] * a1;
                float v1 = acc[d][g4 * 4 + 1] * a0 + Ms[l * 36 + 2 + d * 16 + g4 * 4 + 1] * a1;
                float v2 = acc[d][g4 * 4 + 2] * a0 + Ms[l * 36 + 2 + d * 16 + g4 * 4 + 2] * a1;
                float v3 = acc[d][g4 * 4 + 3] * a0 + Ms[l * 36 + 2 + d * 16 + g4 * 4 + 3] * a1;
                unsigned long long pk = (unsigned long long)cvt_pk_bf16(v0, v1)
                                      | ((unsigned long long)cvt_pk_bf16(v2, v3) << 32);
                *reinterpret_cast<unsigned long long*>(Op + d * 32 + g4 * 8) = pk;
            }
    }
}

extern "C" void kernel_launch(void* const* d_in, const int* in_sizes, int n_in,
                              void* d_out, int out_size, void* d_ws, size_t ws_size,
                              hipStream_t stream) {
    const int S = 2048, HID = 2048, KVD = 512, NQKV = 3072;
    const float* hs = (const float*)d_in[0];
    const float* Wq = (const float*)d_in[1];
    const float* Wk = (const float*)d_in[2];
    const float* Wv = (const float*)d_in[3];
    const float* Wo = (const float*)d_in[4];
    const int* pos  = (const int*)d_in[5];

    char* base = (char*)d_ws;
    auto alloc = [&](size_t bytes) {
        char* r = base;
        base += (bytes + 255) & ~(size_t)255;
        return r;
    };
    unsigned short* hs_b     = (unsigned short*)alloc((size_t)S * HID * 2);
    unsigned short* Wqkv     = (unsigned short*)alloc((size_t)NQKV * HID * 2);
    unsigned short* WoT      = (unsigned short*)alloc((size_t)HID * HID * 2);
    unsigned short* qkv      = (unsigned short*)alloc((size_t)S * NQKV * 2);
    unsigned short* vB       = (unsigned short*)alloc((size_t)KVD * S * 2);
    unsigned short* kBuf     = (unsigned short*)alloc((size_t)KVD * S * 2);
    unsigned short* attn_out = (unsigned short*)alloc((size_t)S * HID * 2);

    // 1. fused prep: all weight transposes + hs cast
    prep_kernel<<<6656, 256, 0, stream>>>(Wq, Wk, Wv, Wo, hs, Wqkv, WoT, hs_b);

    // 2. fused QKV projection, 64x64 tiles (1536 blocks, 5/CU) with RoPE fused in epilogue
    gemm64x64_qkv<<<dim3(NQKV / 64, S / 64), 256, 0, stream>>>(hs_b, Wqkv, qkv, vB, kBuf, pos, S, NQKV, HID);

    // 3. attention: all-register pipeline, coalesced K+V
    attn_kernel<<<2048, 128, 0, stream>>>(qkv, kBuf, vB, attn_out);

    // 4. output projection -> f32: 64x64 tile, 1024 blocks = 4/CU
    gemm64x64_o<<<dim3(HID / 64, S / 64), 256, 0, stream>>>(attn_out, WoT, (float*)d_out, S, HID, HID);
}

// Round 29
// 118.294 us; speedup vs baseline: 1.1046x; 1.1046x over previous
//
#include <hip/hip_runtime.h>
#include <stdint.h>

typedef __attribute__((ext_vector_type(8))) short short8;
typedef __attribute__((ext_vector_type(4))) float floatx4;
typedef __attribute__((ext_vector_type(16))) float floatx16;

__device__ __forceinline__ float b2f(unsigned short u) {
    union { unsigned int i; float f; } x; x.i = ((unsigned int)u) << 16; return x.f;
}
__device__ __forceinline__ unsigned short f2b(float f) {
    unsigned int x = __float_as_uint(f);
    return (unsigned short)((x + 0x7FFFu + ((x >> 16) & 1u)) >> 16);
}
__device__ __forceinline__ unsigned int cvt_pk_bf16(float lo, float hi) {
    unsigned int r;
    asm("v_cvt_pk_bf16_f32 %0, %1, %2" : "=v"(r) : "v"(lo), "v"(hi));
    return r;
}
__device__ __forceinline__ float exp2_(float x) {
    float r;
    asm("v_exp_f32 %0, %1" : "=v"(r) : "v"(x));
    return r;
}

__device__ __forceinline__ void gload_lds16(const void* g, void* l) {
    __builtin_amdgcn_global_load_lds((const __attribute__((address_space(1))) unsigned int*)g,
                                     (__attribute__((address_space(3))) unsigned int*)l, 16, 0, 0);
}

// ---------------- fused prep: 4 weight transposes (f32->bf16) + hs cast, one launch ----------------
__global__ __launch_bounds__(256)
void prep_kernel(const float* __restrict__ Wq, const float* __restrict__ Wk,
                 const float* __restrict__ Wv, const float* __restrict__ Wo,
                 const float* __restrict__ hs,
                 unsigned short* __restrict__ Wqkv, unsigned short* __restrict__ WoT,
                 unsigned short* __restrict__ hs_b) {
    __shared__ float tile[64][65];
    int b = blockIdx.x;
    if (b >= 2560) {
        int i = ((b - 2560) * 256 + threadIdx.x) * 4;
        float4 v = *reinterpret_cast<const float4*>(hs + i);
        hs_b[i + 0] = f2b(v.x);
        hs_b[i + 1] = f2b(v.y);
        hs_b[i + 2] = f2b(v.z);
        hs_b[i + 3] = f2b(v.w);
        return;
    }
    const float* in;
    unsigned short* out;
    int bx, by, ld_in, ld_out;
    if (b < 1024) {
        in = Wq; out = Wqkv; bx = b & 31; by = b >> 5; ld_in = 2048; ld_out = 2048;
    } else if (b < 1280) {
        int c = b - 1024;
        in = Wk; out = Wqkv + (size_t)2048 * 2048; bx = c & 7; by = c >> 3; ld_in = 512; ld_out = 2048;
    } else if (b < 1536) {
        int c = b - 1280;
        in = Wv; out = Wqkv + (size_t)2560 * 2048; bx = c & 7; by = c >> 3; ld_in = 512; ld_out = 2048;
    } else {
        int c = b - 1536;
        in = Wo; out = WoT; bx = c & 31; by = c >> 5; ld_in = 2048; ld_out = 2048;
    }
    int tx = threadIdx.x & 63, ty = threadIdx.x >> 6;
    int c0 = bx * 64, r0 = by * 64;
    #pragma unroll
    for (int i = 0; i < 64; i += 4)
        tile[ty + i][tx] = in[(size_t)(r0 + ty + i) * ld_in + c0 + tx];
    __syncthreads();
    #pragma unroll
    for (int i = 0; i < 64; i += 4)
        out[(size_t)(c0 + ty + i) * ld_out + r0 + tx] = f2b(tile[tx][ty + i]);
}

// ---------------- GEMM: 64x128 tile, BK=64, 4 waves (round-24, proven) -- QKV with fused RoPE ----------------
template<int MODE>
__global__ __launch_bounds__(256)
void gemm64x128(const unsigned short* __restrict__ A, const unsigned short* __restrict__ BT,
                void* __restrict__ Cout, unsigned short* __restrict__ vTout,
                unsigned short* __restrict__ kBout, const int* __restrict__ pos_ids,
                int M, int N, int K) {
    __shared__ __align__(16) unsigned short As[2][64 * 64];
    __shared__ __align__(16) unsigned short Bs[2][128 * 64];
    int tid = threadIdx.x;
    int l = tid & 63, w = tid >> 6;
    int lr = l & 15, lg = l >> 4;

    int gx = gridDim.x;
    int nwg = gx * gridDim.y;
    int flat = blockIdx.y * gx + blockIdx.x;
    int q8 = nwg >> 3;
    int f2 = (flat & 7) * q8 + (flat >> 3);
    int bx = f2 % gx, by = f2 / gx;
    int nb = bx * 128, mb = by * 64;

    floatx4 acc[4][2];
    #pragma unroll
    for (int m = 0; m < 4; ++m)
        #pragma unroll
        for (int f = 0; f < 2; ++f) acc[m][f] = (floatx4)(0.f);

    int ca1 = tid + 256;
    int ra0 = tid >> 3, ja0 = (tid & 7) ^ (ra0 & 7);
    int ra1 = ca1 >> 3, ja1 = (ca1 & 7) ^ (ra1 & 7);
    const unsigned short* Ag0 = A + (size_t)(mb + ra0) * K + ja0 * 8;
    const unsigned short* Ag1 = A + (size_t)(mb + ra1) * K + ja1 * 8;
    const unsigned short* Bg[4];
    #pragma unroll
    for (int i = 0; i < 4; ++i) {
        int c = tid + 256 * i;
        int r = c >> 3, j = (c & 7) ^ (r & 7);
        Bg[i] = BT + (size_t)(nb + r) * K + j * 8;
    }

    auto stage = [&](int buf, int kb) {
        gload_lds16(Ag0 + kb, &As[buf][tid * 8]);
        gload_lds16(Ag1 + kb, &As[buf][ca1 * 8]);
        #pragma unroll
        for (int i = 0; i < 4; ++i)
            gload_lds16(Bg[i] + kb, &Bs[buf][(tid + 256 * i) * 8]);
    };

    int nsteps = K >> 6;
    stage(0, 0);
    for (int it = 0; it < nsteps; ++it) {
        int nxt = (it + 1 < nsteps) ? it + 1 : it;
        stage((it + 1) & 1, nxt * 64);
        asm volatile("s_waitcnt vmcnt(6)" ::: "memory");
        __builtin_amdgcn_s_barrier();
        __builtin_amdgcn_sched_barrier(0);

        const unsigned short* Ab = As[it & 1];
        const unsigned short* Bb = Bs[it & 1];
        #pragma unroll
        for (int kh = 0; kh < 2; ++kh) {
            int sl = ((kh * 4 + lg) ^ (lr & 7)) * 8;
            short8 af[4], bf[2];
            #pragma unroll
            for (int m = 0; m < 4; ++m)
                af[m] = *reinterpret_cast<const short8*>(Ab + (m * 16 + lr) * 64 + sl);
            #pragma unroll
            for (int f = 0; f < 2; ++f)
                bf[f] = *reinterpret_cast<const short8*>(Bb + (w * 32 + f * 16 + lr) * 64 + sl);
            #pragma unroll
            for (int m = 0; m < 4; ++m)
                #pragma unroll
                for (int f = 0; f < 2; ++f)
                    acc[m][f] = __builtin_amdgcn_mfma_f32_16x16x32_bf16(af[m], bf[f], acc[m][f], 0, 0, 0);
        }
        __builtin_amdgcn_sched_barrier(0);
        __builtin_amdgcn_s_barrier();
    }
    asm volatile("s_waitcnt vmcnt(0)" ::: "memory");

    if (MODE == 2 && nb < 2560) {
        // ---- Q or K block: fused RoPE. Pair (i, i+32) spans waves (w, w+1). ----
        float* Xs = (float*)&Bs[0][0];   // 32KB scratch, dead after final barrier
        if (w & 1) {
            float* dst = Xs + ((size_t)(w >> 1) * 64 + l) * 32;
            #pragma unroll
            for (int m = 0; m < 4; ++m)
                #pragma unroll
                for (int f = 0; f < 2; ++f)
                    #pragma unroll
                    for (int r = 0; r < 4; ++r)
                        dst[m * 8 + f * 4 + r] = acc[m][f][r];
        }
        __syncthreads();
        if (!(w & 1)) {
            const float* src = Xs + ((size_t)(w >> 1) * 64 + l) * 32;
            bool isQ = (nb < 2048);
            float qs = isQ ? 0.18033688011112042f : 1.0f; // (1/8)*log2(e) for Q
            int kvh = isQ ? 0 : (((nb - 2048) >> 6) + (w >> 1));
            #pragma unroll
            for (int f = 0; f < 2; ++f) {
                int i = f * 16 + lr;                       // head-relative d, < 32
                float invf = exp2f(-0.41524101186092029f * (float)i);
                int ocol = nb + w * 32 + f * 16 + lr;
                #pragma unroll
                for (int m = 0; m < 4; ++m) {
                    int orow = mb + m * 16 + lg * 4;
                    #pragma unroll
                    for (int r = 0; r < 4; ++r) {
                        int s = orow + r;
                        float pos = (float)pos_ids[s];
                        float sn, cs;
                        __sincosf(pos * invf, &sn, &cs);
                        float x1 = acc[m][f][r];
                        float x2 = src[m * 8 + f * 4 + r];
                        float r1 = (x1 * cs - x2 * sn) * qs;
                        float r2 = (x2 * cs + x1 * sn) * qs;
                        if (isQ) {
                            unsigned short* C = (unsigned short*)Cout;
                            C[(size_t)s * N + ocol]      = f2b(r1);
                            C[(size_t)s * N + ocol + 32] = f2b(r2);
                        } else {
                            int t32 = s >> 5, lq2 = s & 31;
                            int d1 = i, d2 = i + 32;
                            int dc1 = d1 >> 4, hl1 = (d1 >> 3) & 1, e1 = d1 & 7;
                            int dc2 = d2 >> 4, hl2 = (d2 >> 3) & 1, e2 = d2 & 7;
                            size_t tb = (size_t)(kvh * 64 + t32) * 2048;
                            kBout[tb + (size_t)dc1 * 512 + (hl1 * 32 + lq2) * 8 + e1] = f2b(r1);
                            kBout[tb + (size_t)dc2 * 512 + (hl2 * 32 + lq2) * 8 + e2] = f2b(r2);
                        }
                    }
                }
            }
        }
        return;
    }

    #pragma unroll
    for (int m = 0; m < 4; ++m) {
        int orow = mb + m * 16 + lg * 4;
        #pragma unroll
        for (int f = 0; f < 2; ++f) {
            int ocol = nb + w * 32 + f * 16 + lr;
            if (MODE == 2) {
                // V block: fragment-native vB packed write
                int d = ocol - 2560;
                int kvh2 = d >> 6, dd = d & 63, dh = dd >> 5, lq2 = dd & 31;
                int t64 = orow >> 6, so = orow & 63;
                int w2 = so >> 5, so32 = so & 31, kc = so32 >> 4, so16 = so32 & 15;
                int hl2 = so16 >> 3, e0 = so16 & 7;
                size_t addr = ((size_t)((kvh2 * 32 + t64) * 8) + w2 * 4 + dh * 2 + kc) * 512
                            + (hl2 * 32 + lq2) * 8 + e0;
                unsigned long long pk =
                    (unsigned long long)cvt_pk_bf16(acc[m][f][0], acc[m][f][1])
                  | ((unsigned long long)cvt_pk_bf16(acc[m][f][2], acc[m][f][3]) << 32);
                *reinterpret_cast<unsigned long long*>(vTout + addr) = pk;
            } else {
                #pragma unroll
                for (int r = 0; r < 4; ++r) {
                    if (MODE == 1)
                        ((float*)Cout)[(size_t)(orow + r) * N + ocol] = acc[m][f][r];
                    else
                        ((unsigned short*)Cout)[(size_t)(orow + r) * N + ocol] = f2b(acc[m][f][r]);
                }
            }
        }
    }
}

// ---------------- O-proj GEMM: 64x64 tile, BK=64, 4 waves (2x2, wave tile 32x32) ----------------
__global__ __launch_bounds__(256)
void gemm64x64_o(const unsigned short* __restrict__ A, const unsigned short* __restrict__ BT,
                 float* __restrict__ Cout, int M, int N, int K) {
    __shared__ __align__(16) unsigned short As[2][64 * 64];
    __shared__ __align__(16) unsigned short Bs[2][64 * 64];
    int tid = threadIdx.x;
    int l = tid & 63, w = tid >> 6;
    int lr = l & 15, lg = l >> 4;
    int wr = w >> 1, wc = w & 1;

    int gx = gridDim.x;
    int nwg = gx * gridDim.y;
    int flat = blockIdx.y * gx + blockIdx.x;
    int q8 = nwg >> 3;
    int f2 = (flat & 7) * q8 + (flat >> 3);
    int bx = f2 % gx, by = f2 / gx;
    int nb = bx * 64, mb = by * 64;

    floatx4 acc[2][2];
    #pragma unroll
    for (int m = 0; m < 2; ++m)
        #pragma unroll
        for (int f = 0; f < 2; ++f) acc[m][f] = (floatx4)(0.f);

    const unsigned short* Ag[2];
    const unsigned short* Bg[2];
    #pragma unroll
    for (int i = 0; i < 2; ++i) {
        int c = tid + 256 * i;
        int r = c >> 3, j = (c & 7) ^ (r & 7);
        Ag[i] = A + (size_t)(mb + r) * K + j * 8;
        Bg[i] = BT + (size_t)(nb + r) * K + j * 8;
    }

    auto stage = [&](int buf, int kb) {
        #pragma unroll
        for (int i = 0; i < 2; ++i) {
            gload_lds16(Ag[i] + kb, &As[buf][(tid + 256 * i) * 8]);
            gload_lds16(Bg[i] + kb, &Bs[buf][(tid + 256 * i) * 8]);
        }
    };

    int nsteps = K >> 6;
    stage(0, 0);
    for (int it = 0; it < nsteps; ++it) {
        int nxt = (it + 1 < nsteps) ? it + 1 : it;
        stage((it + 1) & 1, nxt * 64);
        asm volatile("s_waitcnt vmcnt(4)" ::: "memory");
        __builtin_amdgcn_s_barrier();
        __builtin_amdgcn_sched_barrier(0);

        const unsigned short* Ab = As[it & 1];
        const unsigned short* Bb = Bs[it & 1];
        #pragma unroll
        for (int kh = 0; kh < 2; ++kh) {
            int sl = ((kh * 4 + lg) ^ (lr & 7)) * 8;
            short8 af[2], bf[2];
            #pragma unroll
            for (int m = 0; m < 2; ++m)
                af[m] = *reinterpret_cast<const short8*>(Ab + (wr * 32 + m * 16 + lr) * 64 + sl);
            #pragma unroll
            for (int f = 0; f < 2; ++f)
                bf[f] = *reinterpret_cast<const short8*>(Bb + (wc * 32 + f * 16 + lr) * 64 + sl);
            #pragma unroll
            for (int m = 0; m < 2; ++m)
                #pragma unroll
                for (int f = 0; f < 2; ++f)
                    acc[m][f] = __builtin_amdgcn_mfma_f32_16x16x32_bf16(af[m], bf[f], acc[m][f], 0, 0, 0);
        }
        __builtin_amdgcn_sched_barrier(0);
        __builtin_amdgcn_s_barrier();
    }
    asm volatile("s_waitcnt vmcnt(0)" ::: "memory");

    #pragma unroll
    for (int m = 0; m < 2; ++m) {
        int orow = mb + wr * 32 + m * 16 + lg * 4;
        #pragma unroll
        for (int f = 0; f < 2; ++f) {
            int ocol = nb + wc * 32 + f * 16 + lr;
            #pragma unroll
            for (int r = 0; r < 4; ++r)
                Cout[(size_t)(orow + r) * N + ocol] = acc[m][f][r];
        }
    }
}

// ---------------- causal GQA flash attention (round-20, proven): all-register, coalesced K+V ----------------
__global__ __launch_bounds__(128, 2)
void attn_kernel(const unsigned short* __restrict__ QKV, // [2048][3072] bf16 (q only used)
                 const unsigned short* __restrict__ KB,  // kB fragment layout, 2MB
                 const unsigned short* __restrict__ VB,  // vB fragment layout, 2MB
                 unsigned short* __restrict__ O) {       // [2048][2048] bf16
    const int LDQ = 3072, HID = 2048;
    __shared__ float Ms[64 * 36];

    int tid = threadIdx.x;
    int l = tid & 63, w = tid >> 6;        // 2 waves
    int lq = l & 31, hl = l >> 5;
    int b = blockIdx.x;
    int h = b & 31;
    int band = 63 - (b >> 5);               // heavy bands first
    int nT = (band >> 1) + 1;               // 64-key tiles
    int kvh = h >> 2;
    int qrow = band * 32 + lq;

    short8 qf[4];
    {
        const unsigned short* Qr = QKV + (size_t)qrow * LDQ + h * 64;
        #pragma unroll
        for (int c = 0; c < 4; ++c)
            qf[c] = *reinterpret_cast<const short8*>(Qr + c * 16 + hl * 8);
    }

    const unsigned short* Kp = KB + ((size_t)(kvh * 64 + w) * 4) * 512 + l * 8;
    const size_t KSTEP = 2 * 4 * 512;
    const unsigned short* Vbase = VB + ((size_t)kvh * 32 * 8 + (size_t)w * 4) * 512 + l * 8;

    floatx16 acc[2];
    acc[0] = (floatx16)(0.f); acc[1] = (floatx16)(0.f);
    float m_run = -1e30f, l_run = 0.f;

    auto process = [&](const short8* kf, int c0w, bool diag,
                       short8 v00, short8 v01, short8 v10, short8 v11) {
        floatx16 st = (floatx16)(0.f);
        __builtin_amdgcn_s_setprio(1);
        #pragma unroll
        for (int dc = 0; dc < 4; ++dc)
            st = __builtin_amdgcn_mfma_f32_32x32x16_bf16(kf[dc], qf[dc], st, 0, 0, 0);
        __builtin_amdgcn_s_setprio(0);
        if (diag) {
            #pragma unroll
            for (int r = 0; r < 16; ++r) {
                int key = c0w + (r & 3) + 8 * (r >> 2) + 4 * hl;
                if (key > qrow) st[r] = -1e30f;
            }
        }
        float t0 = fmaxf(fmaxf(st[0], st[1]), fmaxf(st[2], st[3]));
        float t1 = fmaxf(fmaxf(st[4], st[5]), fmaxf(st[6], st[7]));
        float t2 = fmaxf(fmaxf(st[8], st[9]), fmaxf(st[10], st[11]));
        float t3 = fmaxf(fmaxf(st[12], st[13]), fmaxf(st[14], st[15]));
        float tm = fmaxf(fmaxf(t0, t1), fmaxf(t2, t3));
        tm = fmaxf(tm, __shfl_xor(tm, 32));
        if (!__all(tm <= m_run + 11.5f)) {
            float mn = fmaxf(m_run, tm);
            float al = exp2_(m_run - mn);
            l_run *= al;
            acc[0] *= al;
            acc[1] *= al;
            m_run = mn;
        }
        float p[16];
        #pragma unroll
        for (int r = 0; r < 16; ++r) p[r] = exp2_(st[r] - m_run);
        float s0 = (p[0] + p[1]) + (p[2] + p[3]);
        float s1 = (p[4] + p[5]) + (p[6] + p[7]);
        float s2 = (p[8] + p[9]) + (p[10] + p[11]);
        float s3 = (p[12] + p[13]) + (p[14] + p[15]);
        float rs = (s0 + s1) + (s2 + s3);
        rs += __shfl_xor(rs, 32);
        l_run += rs;
        unsigned int u[4][2];
        #pragma unroll
        for (int B2 = 0; B2 < 4; ++B2) {
            u[B2][0] = cvt_pk_bf16(p[B2 * 4 + 0], p[B2 * 4 + 1]);
            u[B2][1] = cvt_pk_bf16(p[B2 * 4 + 2], p[B2 * 4 + 3]);
        }
        asm volatile("s_waitcnt vmcnt(4)" ::: "memory"); // V(j) landed; K(j+1) in flight
        __builtin_amdgcn_sched_barrier(0);
        #pragma unroll
        for (int kc = 0; kc < 2; ++kc) {
            unsigned int o0 = u[2 * kc][0],     o1 = u[2 * kc][1];
            unsigned int e0 = u[2 * kc + 1][0], e1 = u[2 * kc + 1][1];
            unsigned int t0x = (unsigned int)__shfl((int)o0, l ^ 32);
            unsigned int t1x = (unsigned int)__shfl((int)o1, l ^ 32);
            unsigned int s0p = (unsigned int)__shfl((int)e0, l ^ 32);
            unsigned int s1p = (unsigned int)__shfl((int)e1, l ^ 32);
            union { unsigned int uu[4]; short8 s8; } pf;
            pf.uu[0] = hl ? s0p : o0;
            pf.uu[1] = hl ? s1p : o1;
            pf.uu[2] = hl ? e0 : t0x;
            pf.uu[3] = hl ? e1 : t1x;
            __builtin_amdgcn_s_setprio(1);
            acc[0] = __builtin_amdgcn_mfma_f32_32x32x16_bf16(kc ? v01 : v00, pf.s8, acc[0], 0, 0, 0);
            acc[1] = __builtin_amdgcn_mfma_f32_32x32x16_bf16(kc ? v11 : v10, pf.s8, acc[1], 0, 0, 0);
            __builtin_amdgcn_s_setprio(0);
        }
    };

    short8 kA[4], kBr[4];
    #pragma unroll
    for (int dc = 0; dc < 4; ++dc)
        kA[dc] = *reinterpret_cast<const short8*>(Kp + dc * 512);

    int j = 0;
    while (true) {
        {
            bool last = (j == nT - 1);
            const unsigned short* Vs = Vbase + (size_t)j * 8 * 512;
            short8 v00 = *reinterpret_cast<const short8*>(Vs);
            short8 v01 = *reinterpret_cast<const short8*>(Vs + 512);
            short8 v10 = *reinterpret_cast<const short8*>(Vs + 1024);
            short8 v11 = *reinterpret_cast<const short8*>(Vs + 1536);
            __builtin_amdgcn_sched_barrier(0);
            const unsigned short* Kn = last ? Kp : Kp + KSTEP;
            #pragma unroll
            for (int dc = 0; dc < 4; ++dc)
                kBr[dc] = *reinterpret_cast<const short8*>(Kn + dc * 512);
            asm volatile("s_waitcnt vmcnt(8)" ::: "memory");
            __builtin_amdgcn_sched_barrier(0);
            process(kA, j * 64 + w * 32, last, v00, v01, v10, v11);
            if (last) break;
            ++j; Kp = Kn;
        }
        {
            bool last = (j == nT - 1);
            const unsigned short* Vs = Vbase + (size_t)j * 8 * 512;
            short8 v00 = *reinterpret_cast<const short8*>(Vs);
            short8 v01 = *reinterpret_cast<const short8*>(Vs + 512);
            short8 v10 = *reinterpret_cast<const short8*>(Vs + 1024);
            short8 v11 = *reinterpret_cast<const short8*>(Vs + 1536);
            __builtin_amdgcn_sched_barrier(0);
            const unsigned short* Kn = last ? Kp : Kp + KSTEP;
            #pragma unroll
            for (int dc = 0; dc < 4; ++dc)
                kA[dc] = *reinterpret_cast<const short8*>(Kn + dc * 512);
            asm volatile("s_waitcnt vmcnt(8)" ::: "memory");
            __builtin_amdgcn_sched_barrier(0);
            process(kBr, j * 64 + w * 32, last, v00, v01, v10, v11);
            if (last) break;
            ++j; Kp = Kn;
        }
    }
    asm volatile("s_waitcnt vmcnt(0)" ::: "memory");
    __syncthreads();

    if (w == 1) {
        Ms[l * 36 + 0] = m_run;
        Ms[l * 36 + 1] = l_run;
        #pragma unroll
        for (int d = 0; d < 2; ++d)
            #pragma unroll
            for (int r = 0; r < 16; ++r)
                Ms[l * 36 + 2 + d * 16 + r] = acc[d][r];
    }
    __syncthreads();
    if (w == 0) {
        float m1 = Ms[l * 36 + 0], l1 = Ms[l * 36 + 1];
        float mm = fmaxf(m_run, m1);
        float a0 = exp2_(m_run - mm), a1 = exp2_(m1 - mm);
        float inv = 1.0f / (l_run * a0 + l1 * a1);
        a0 *= inv; a1 *= inv;
        unsigned short* Op = O + (size_t)qrow * HID + h * 64 + hl * 4;
        #pragma unroll
        for (int d = 0; d < 2; ++d)
            #pragma unroll
            for (int g4 = 0; g4 < 4; ++g4) {
                float v0 = acc[d][g4 * 4 + 0] * a0 + Ms[l * 36 + 2 + d * 16 + g4 * 4 + 0] * a1;
                float v1 = acc[d][g4 * 4 + 1] * a0 + Ms[l * 36 + 2 + d * 16 + g4 * 4 + 1] * a1;
                float v2 = acc[d][g4 * 4 + 2] * a0 + Ms[l * 36 + 2 + d * 16 + g4 * 4 + 2] * a1;
                float v3 = acc[d][g4 * 4 + 3] * a0 + Ms[l * 36 + 2 + d * 16 + g4 * 4 + 3] * a1;
                unsigned long long pk = (unsigned long long)cvt_pk_bf16(v0, v1)
                                      | ((unsigned long long)cvt_pk_bf16(v2, v3) << 32);
                *reinterpret_cast<unsigned long long*>(Op + d * 32 + g4 * 8) = pk;
            }
    }
}

extern "C" void kernel_launch(void* const* d_in, const int* in_sizes, int n_in,
                              void* d_out, int out_size, void* d_ws, size_t ws_size,
                              hipStream_t stream) {
    const int S = 2048, HID = 2048, KVD = 512, NQKV = 3072;
    const float* hs = (const float*)d_in[0];
    const float* Wq = (const float*)d_in[1];
    const float* Wk = (const float*)d_in[2];
    const float* Wv = (const float*)d_in[3];
    const float* Wo = (const float*)d_in[4];
    const int* pos  = (const int*)d_in[5];

    char* base = (char*)d_ws;
    auto alloc = [&](size_t bytes) {
        char* r = base;
        base += (bytes + 255) & ~(size_t)255;
        return r;
    };
    unsigned short* hs_b     = (unsigned short*)alloc((size_t)S * HID * 2);
    unsigned short* Wqkv     = (unsigned short*)alloc((size_t)NQKV * HID * 2);
    unsigned short* WoT      = (unsigned short*)alloc((size_t)HID * HID * 2);
    unsigned short* qkv      = (unsigned short*)alloc((size_t)S * NQKV * 2);
    unsigned short* vB       = (unsigned short*)alloc((size_t)KVD * S * 2);
    unsigned short* kBuf     = (unsigned short*)alloc((size_t)KVD * S * 2);
    unsigned short* attn_out = (unsigned short*)alloc((size_t)S * HID * 2);

    // 1. fused prep: all weight transposes + hs cast
    prep_kernel<<<6656, 256, 0, stream>>>(Wq, Wk, Wv, Wo, hs, Wqkv, WoT, hs_b);

    // 2. fused QKV projection with RoPE fused in epilogue
    gemm64x128<2><<<dim3(NQKV / 128, S / 64), 256, 0, stream>>>(hs_b, Wqkv, qkv, vB, kBuf, pos, S, NQKV, HID);

    // 3. attention: all-register pipeline, coalesced K+V
    attn_kernel<<<2048, 128, 0, stream>>>(qkv, kBuf, vB, attn_out);

    // 4. output projection -> f32: 64x64 tile, 1024 blocks = 4/CU
    gemm64x64_o<<<dim3(HID / 64, S / 64), 256, 0, stream>>>(attn_out, WoT, (float*)d_out, S, HID, HID);
}